// Round 5
// baseline (239.357 us; speedup 1.0000x reference)
//
#include <hip/hip_runtime.h>
#include <hip/hip_bf16.h>
#include <stdint.h>

#define T_TOK 4096
#define DH 1024
#define DI 1408
#define NE 8
#define TOPK 2
#define PADROWS 10240   // 8192 assignments + up to 8*255 pad (256-row tiles)

typedef short s16x8 __attribute__((ext_vector_type(8)));
typedef float f32x4 __attribute__((ext_vector_type(4)));

__device__ inline unsigned f2bf(float f) {
    __hip_bfloat16 h = __float2bfloat16(f);
    return (unsigned)*(unsigned short*)&h;
}

#define GLDS(src, dst) __builtin_amdgcn_global_load_lds( \
    (const __attribute__((address_space(1))) void*)(src), \
    (__attribute__((address_space(3))) void*)(dst), 16, 0, 0)

// ---------------- fp32 -> bf16 bulk convert (3 weight tensors, one launch) ----------------
__global__ __launch_bounds__(256) void cvt3_kernel(const float* __restrict__ s0,
        const float* __restrict__ s1, const float* __restrict__ s2,
        unsigned short* __restrict__ t0, unsigned short* __restrict__ t1,
        unsigned short* __restrict__ t2, int n4) {
    const float* src = blockIdx.y == 0 ? s0 : (blockIdx.y == 1 ? s1 : s2);
    unsigned short* dst = blockIdx.y == 0 ? t0 : (blockIdx.y == 1 ? t1 : t2);
    int i = blockIdx.x * blockDim.x + threadIdx.x;
    int stride = gridDim.x * blockDim.x;
    for (; i < n4; i += stride) {
        float4 v = ((const float4*)src)[i];
        uint2 o;
        o.x = f2bf(v.x) | (f2bf(v.y) << 16);
        o.y = f2bf(v.z) | (f2bf(v.w) << 16);
        ((uint2*)dst)[i] = o;
    }
}

// ---------------- router: logits, softmax, top-2, renorm; x->bf16. NO atomics ----------------
__global__ __launch_bounds__(256) void router_kernel(const float* __restrict__ x,
                              const float* __restrict__ gw,
                              float* __restrict__ logits_out,
                              int* __restrict__ tokE, float* __restrict__ tokW,
                              unsigned short* __restrict__ xb) {
    int wave = threadIdx.x >> 6;
    int lane = threadIdx.x & 63;
    int t = blockIdx.x * 4 + wave;
    const float4* xr = (const float4*)(x + (size_t)t * DH);

    float acc[NE];
#pragma unroll
    for (int e = 0; e < NE; ++e) acc[e] = 0.f;

#pragma unroll
    for (int i = 0; i < 4; ++i) {
        float4 xv = xr[lane + i * 64];
#pragma unroll
        for (int e = 0; e < NE; ++e) {
            float4 g = ((const float4*)(gw + (size_t)e * DH))[lane + i * 64];
            acc[e] += xv.x * g.x + xv.y * g.y + xv.z * g.z + xv.w * g.w;
        }
        uint2 o;
        o.x = f2bf(xv.x) | (f2bf(xv.y) << 16);
        o.y = f2bf(xv.z) | (f2bf(xv.w) << 16);
        *(uint2*)(xb + (size_t)t * DH + (lane + i * 64) * 4) = o;
    }
#pragma unroll
    for (int e = 0; e < NE; ++e) {
#pragma unroll
        for (int off = 32; off > 0; off >>= 1) acc[e] += __shfl_xor(acc[e], off, 64);
    }
    if (lane == 0) {
        float mx = acc[0];
#pragma unroll
        for (int e = 1; e < NE; ++e) mx = fmaxf(mx, acc[e]);
        float p[NE]; float s = 0.f;
#pragma unroll
        for (int e = 0; e < NE; ++e) { p[e] = expf(acc[e] - mx); s += p[e]; }
        float inv = 1.f / s;
#pragma unroll
        for (int e = 0; e < NE; ++e) p[e] *= inv;
        int i0 = 0, i1 = -1; float p0 = -1.f, p1 = -1.f;
#pragma unroll
        for (int e = 0; e < NE; ++e) {
            float v = p[e];
            if (v > p0) { p1 = p0; i1 = i0; p0 = v; i0 = e; }
            else if (v > p1) { p1 = v; i1 = e; }
        }
        float wsum = p0 + p1;
#pragma unroll
        for (int e = 0; e < NE; ++e) logits_out[(size_t)t * NE + e] = acc[e];
        tokE[2 * t]     = i0;  tokE[2 * t + 1] = i1;
        tokW[2 * t]     = p0 / wsum;  tokW[2 * t + 1] = p1 / wsum;
    }
}

// ---------------- histogram + prefix (pad 256): single block, ballot popcounts ----------------
__global__ __launch_bounds__(256) void hist_kernel(const int* __restrict__ tokE,
        int* __restrict__ counts, int* __restrict__ padOff) {
    __shared__ int wc[4][NE];
    int tid = threadIdx.x;
    int wave = tid >> 6, lane = tid & 63;
    int cnt[NE];
#pragma unroll
    for (int e = 0; e < NE; ++e) cnt[e] = 0;
    for (int i = tid; i < T_TOK * TOPK; i += 256) {
        int v = tokE[i];
#pragma unroll
        for (int e = 0; e < NE; ++e)
            cnt[e] += (int)__popcll(__ballot(v == e));
    }
    if (lane == 0) {
#pragma unroll
        for (int e = 0; e < NE; ++e) wc[wave][e] = cnt[e];
    }
    __syncthreads();
    if (tid == 0) {
        int r = 0;
        for (int e = 0; e < NE; ++e) {
            int c = wc[0][e] + wc[1][e] + wc[2][e] + wc[3][e];
            counts[e] = c;
            padOff[e] = r;
            r += ((c + 255) >> 8) << 8;
        }
        padOff[NE] = r;
    }
}

// ---------------- scatter: wave-aggregated cursor atomics ----------------
__global__ __launch_bounds__(256) void scatter_kernel(const int* __restrict__ tokE,
                               const int* __restrict__ padOff, int* __restrict__ cursor,
                               int* __restrict__ assignTok, int* __restrict__ tokSlot) {
    int t = blockIdx.x * blockDim.x + threadIdx.x;
    int lane = threadIdx.x & 63;
    unsigned long long lmask = (1ull << lane) - 1ull;
#pragma unroll
    for (int k = 0; k < TOPK; ++k) {
        int e = tokE[2 * t + k];
#pragma unroll
        for (int ex = 0; ex < NE; ++ex) {
            unsigned long long m = __ballot(e == ex);
            if (e == ex) {
                int rank = (int)__popcll(m & lmask);
                int leader = __ffsll((long long)m) - 1;
                int b = 0;
                if (rank == 0) b = atomicAdd(&cursor[ex], (int)__popcll(m));
                b = __shfl(b, leader, 64);
                int slot = padOff[ex] + b + rank;
                assignTok[slot] = t;
                tokSlot[2 * t + k] = slot;
            }
        }
    }
}

// ---------------- grouped GEMM A: h = silu(xb[tok] Wg^T) * (xb[tok] Wu^T) ----------------
// 256x128 tile, double-buffered LDS, prefetch-before-compute, XCD swizzle.
__global__ __launch_bounds__(512) void gemmA_kernel(
        const unsigned short* __restrict__ xb,
        const unsigned short* __restrict__ gpb, const unsigned short* __restrict__ upb,
        const int* __restrict__ padOff, const int* __restrict__ assignTok,
        unsigned short* __restrict__ h) {
    // 440 blocks = 8 XCDs * 55; col-major linearization -> same-expert/same-panel
    // row blocks land on one XCD's L2.
    int bid = blockIdx.x;
    int nid = (bid & 7) * 55 + (bid >> 3);
    int colblk = nid / 40, rowblk = nid - colblk * 40;
    int pr0 = rowblk * 256;
    int n0 = colblk * 128;
    int e = -1;
#pragma unroll
    for (int i = 0; i < NE; ++i)
        if (pr0 >= padOff[i] && pr0 < padOff[i + 1]) e = i;
    if (e < 0) return;

    __shared__ unsigned short As[2][256 * 32];   // 16 KB each
    __shared__ unsigned short Bgs[2][128 * 32];  // 8 KB each
    __shared__ unsigned short Bus[2][128 * 32];

    int tid = threadIdx.x;
    int lane = tid & 63;
    int w = tid >> 6;
    int wm = (w >> 2) * 128;    // wave M offset (0/128)
    int wn = (w & 3) * 32;      // wave N offset (0/32/64/96)

    int tok0 = assignTok[pr0 + w * 16 + (lane >> 2)];
    int tok1 = assignTok[pr0 + 128 + w * 16 + (lane >> 2)];
    const unsigned short* a0 = xb + (size_t)tok0 * DH + (lane & 3) * 8;
    const unsigned short* a1 = xb + (size_t)tok1 * DH + (lane & 3) * 8;
    int brow = n0 + (tid >> 2);
    const unsigned short* gsrc = gpb + ((size_t)e * DI + brow) * DH + (tid & 3) * 8;
    const unsigned short* usrc = upb + ((size_t)e * DI + brow) * DH + (tid & 3) * 8;

    f32x4 accG[8][2], accU[8][2];
#pragma unroll
    for (int i = 0; i < 8; ++i)
#pragma unroll
        for (int j = 0; j < 2; ++j) {
            accG[i][j] = (f32x4){0.f, 0.f, 0.f, 0.f};
            accU[i][j] = (f32x4){0.f, 0.f, 0.f, 0.f};
        }

#define STAGE_A(buf, k0) do { \
    GLDS(a0 + (k0),   &As[buf][w * 512]); \
    GLDS(a1 + (k0),   &As[buf][4096 + w * 512]); \
    GLDS(gsrc + (k0), &Bgs[buf][w * 512]); \
    GLDS(usrc + (k0), &Bus[buf][w * 512]); \
    } while (0)

    STAGE_A(0, 0);
    __syncthreads();

    for (int ks = 0; ks < 32; ++ks) {
        int cur = ks & 1;
        if (ks < 31) STAGE_A(cur ^ 1, (ks + 1) * 32);

        s16x8 af[8], bgf[2], buf_[2];
#pragma unroll
        for (int i = 0; i < 8; ++i)
            af[i] = *(const s16x8*)&As[cur][(wm + 16 * i + (lane & 15)) * 32 + (lane >> 4) * 8];
#pragma unroll
        for (int j = 0; j < 2; ++j) {
            bgf[j]  = *(const s16x8*)&Bgs[cur][(wn + 16 * j + (lane & 15)) * 32 + (lane >> 4) * 8];
            buf_[j] = *(const s16x8*)&Bus[cur][(wn + 16 * j + (lane & 15)) * 32 + (lane >> 4) * 8];
        }
#pragma unroll
        for (int i = 0; i < 8; ++i)
#pragma unroll
            for (int j = 0; j < 2; ++j) {
                accG[i][j] = __builtin_amdgcn_mfma_f32_16x16x32_bf16(af[i], bgf[j], accG[i][j], 0, 0, 0);
                accU[i][j] = __builtin_amdgcn_mfma_f32_16x16x32_bf16(af[i], buf_[j], accU[i][j], 0, 0, 0);
            }
        __syncthreads();
    }
#undef STAGE_A

#pragma unroll
    for (int i = 0; i < 8; ++i) {
        int rowb = pr0 + wm + 16 * i + ((lane >> 4) << 2);
#pragma unroll
        for (int j = 0; j < 2; ++j) {
            int col = n0 + wn + 16 * j + (lane & 15);
#pragma unroll
            for (int r = 0; r < 4; ++r) {
                float g = accG[i][j][r], u = accU[i][j][r];
                float val = (g / (1.f + __expf(-g))) * u;
                h[(size_t)(rowb + r) * DI + col] = (unsigned short)f2bf(val);
            }
        }
    }
}

// ---------------- grouped GEMM B: outP = h Wd^T ----------------
__global__ __launch_bounds__(512) void gemmB_kernel(
        const unsigned short* __restrict__ h,
        const unsigned short* __restrict__ dpb,
        const int* __restrict__ padOff, const int* __restrict__ counts,
        float* __restrict__ outP) {
    // 320 blocks = 8 XCDs * 40; each XCD owns exactly one column panel.
    int bid = blockIdx.x;
    int nid = (bid & 7) * 40 + (bid >> 3);
    int colblk = nid / 40, rowblk = nid - colblk * 40;
    int pr0 = rowblk * 256;
    int n0 = colblk * 128;
    int e = -1, base = 0;
#pragma unroll
    for (int i = 0; i < NE; ++i)
        if (pr0 >= padOff[i] && pr0 < padOff[i + 1]) { e = i; base = padOff[i]; }
    if (e < 0) return;
    int cnt = counts[e];

    __shared__ unsigned short As[2][256 * 32];
    __shared__ unsigned short Bs[2][128 * 32];

    int tid = threadIdx.x;
    int lane = tid & 63;
    int w = tid >> 6;
    int wm = (w >> 2) * 128;
    int wn = (w & 3) * 32;

    const unsigned short* a0 = h + (size_t)(pr0 + w * 16 + (lane >> 2)) * DI + (lane & 3) * 8;
    const unsigned short* a1 = h + (size_t)(pr0 + 128 + w * 16 + (lane >> 2)) * DI + (lane & 3) * 8;
    int brow = n0 + (tid >> 2);
    const unsigned short* bsrc = dpb + ((size_t)e * DH + brow) * DI + (tid & 3) * 8;

    f32x4 acc[8][2];
#pragma unroll
    for (int i = 0; i < 8; ++i)
#pragma unroll
        for (int j = 0; j < 2; ++j) acc[i][j] = (f32x4){0.f, 0.f, 0.f, 0.f};

#define STAGE_B(buf, k0) do { \
    GLDS(a0 + (k0),   &As[buf][w * 512]); \
    GLDS(a1 + (k0),   &As[buf][4096 + w * 512]); \
    GLDS(bsrc + (k0), &Bs[buf][w * 512]); \
    } while (0)

    STAGE_B(0, 0);
    __syncthreads();

    for (int ks = 0; ks < 44; ++ks) {
        int cur = ks & 1;
        if (ks < 43) STAGE_B(cur ^ 1, (ks + 1) * 32);

        s16x8 af[8], bf[2];
#pragma unroll
        for (int i = 0; i < 8; ++i)
            af[i] = *(const s16x8*)&As[cur][(wm + 16 * i + (lane & 15)) * 32 + (lane >> 4) * 8];
#pragma unroll
        for (int j = 0; j < 2; ++j)
            bf[j] = *(const s16x8*)&Bs[cur][(wn + 16 * j + (lane & 15)) * 32 + (lane >> 4) * 8];
#pragma unroll
        for (int i = 0; i < 8; ++i)
#pragma unroll
            for (int j = 0; j < 2; ++j)
                acc[i][j] = __builtin_amdgcn_mfma_f32_16x16x32_bf16(af[i], bf[j], acc[i][j], 0, 0, 0);
        __syncthreads();
    }
#undef STAGE_B

#pragma unroll
    for (int i = 0; i < 8; ++i) {
        int rowb = pr0 + wm + 16 * i + ((lane >> 4) << 2);
#pragma unroll
        for (int r = 0; r < 4; ++r) {
            int prow = rowb + r;
            if (prow - base < cnt) {
#pragma unroll
                for (int j = 0; j < 2; ++j) {
                    int col = n0 + wn + 16 * j + (lane & 15);
                    outP[(size_t)prow * DH + col] = acc[i][j][r];
                }
            }
        }
    }
}

// ---------------- combine: out[t] = w0*outP[s0] + w1*outP[s1] ----------------
__global__ __launch_bounds__(256) void combine_kernel(const float* __restrict__ outP,
        const int* __restrict__ tokSlot, const float* __restrict__ tokW,
        float* __restrict__ out) {
    int t = blockIdx.x;
    int c = threadIdx.x * 4;
    int s0 = tokSlot[2 * t], s1 = tokSlot[2 * t + 1];
    float w0 = tokW[2 * t], w1 = tokW[2 * t + 1];
    float4 a = *(const float4*)(outP + (size_t)s0 * DH + c);
    float4 b = *(const float4*)(outP + (size_t)s1 * DH + c);
    float4 o;
    o.x = w0 * a.x + w1 * b.x;
    o.y = w0 * a.y + w1 * b.y;
    o.z = w0 * a.z + w1 * b.z;
    o.w = w0 * a.w + w1 * b.w;
    *(float4*)(out + (size_t)t * DH + c) = o;
}

extern "C" void kernel_launch(void* const* d_in, const int* in_sizes, int n_in,
                              void* d_out, int out_size, void* d_ws, size_t ws_size,
                              hipStream_t stream) {
    const float* x  = (const float*)d_in[0];
    const float* gw = (const float*)d_in[1];
    const float* gp = (const float*)d_in[2];
    const float* up = (const float*)d_in[3];
    const float* dp = (const float*)d_in[4];
    float* out = (float*)d_out;
    float* logits = out + (size_t)T_TOK * DH;

    char* ws = (char*)d_ws;
    int*   counts    = (int*)(ws + 0);
    int*   cursor    = (int*)(ws + 64);
    int*   padOff    = (int*)(ws + 128);
    int*   tokE      = (int*)(ws + 4096);                       // 32 KB
    float* tokW      = (float*)(ws + 36864);                    // 32 KB
    int*   tokSlot   = (int*)(ws + 69632);                      // 32 KB
    int*   assignTok = (int*)(ws + 102400);                     // 40 KB (PADROWS ints)
    unsigned short* xb  = (unsigned short*)(ws + 147456);       // 8.39 MB
    unsigned short* gpb = (unsigned short*)(ws + 8536064);      // 23.07 MB
    unsigned short* upb = (unsigned short*)(ws + 31604736);     // 23.07 MB
    unsigned short* dpb = (unsigned short*)(ws + 54673408);     // 23.07 MB
    unsigned short* h   = (unsigned short*)(ws + 77742080);     // 28.84 MB
    float* outP = (float*)(ws + 8536064);  // 41.9 MB, overlaps gpb/upb (dead after gemmA)

    hipMemsetAsync(ws, 0, 256, stream);
    hipMemsetAsync(ws + 102400, 0, PADROWS * 4, stream);  // assignTok pad -> token 0

    const int NW4 = NE * DI * DH / 4;
    cvt3_kernel<<<dim3(1024, 3), 256, 0, stream>>>(gp, up, dp, gpb, upb, dpb, NW4);

    router_kernel<<<T_TOK / 4, 256, 0, stream>>>(x, gw, logits, tokE, tokW, xb);
    hist_kernel<<<1, 256, 0, stream>>>(tokE, counts, padOff);
    scatter_kernel<<<T_TOK / 256, 256, 0, stream>>>(tokE, padOff, cursor, assignTok, tokSlot);

    gemmA_kernel<<<dim3((DI / 128) * (PADROWS / 256)), 512, 0, stream>>>(xb, gpb, upb, padOff, assignTok, h);
    gemmB_kernel<<<dim3((DH / 128) * (PADROWS / 256)), 512, 0, stream>>>(h, dpb, padOff, counts, outP);
    combine_kernel<<<T_TOK, 256, 0, stream>>>(outP, tokSlot, tokW, out);
}